// Round 4
// baseline (137.052 us; speedup 1.0000x reference)
//
#include <hip/hip_runtime.h>
#include <math.h>

// Problem constants
#define DD     2048
#define EE     64
#define NTOK   8192
#define BM     32               // tokens per m-tile
#define KSPLIT 4                // K-split across blockIdx.y (512 k each)
#define NKS    16               // ksteps (16 k) per wave (256 k)

// Output layout (all read back as float32 by harness)
#define PROB_OFF 0
#define IDX_OFF  524288
#define MASK_OFF 540672
#define MASK_K_STRIDE (NTOK * EE)

typedef __bf16 bf16x8 __attribute__((ext_vector_type(8)));
typedef float  f32x16 __attribute__((ext_vector_type(16)));

__device__ __forceinline__ unsigned f2bf_rne(float f) {
  unsigned u = __float_as_uint(f);
  return (u + 0x7fffu + ((u >> 16) & 1u)) >> 16;   // low 16 bits = bf16
}
__device__ __forceinline__ float bf2f(unsigned h) {
  return __uint_as_float(h << 16);
}

// ---------------------------------------------------------------------------
// prep_w: weights -> MFMA-fragment-ready bf16 hi/lo in workspace (1 MB).
// Fragment bijection (validated end-to-end by R1/R2/R3 passes):
//   slot (g, nt, mat, lane, i)  <->  B[k][c],  k = 16*g + 8*(lane>>5) + i,
//   c = 32*nt + (lane&31),  (c<64 -> gate, else noise).
// Byte addr = ((g*4 + nt)*2 + mat)*1024 + lane*16 + 2*i.
// ---------------------------------------------------------------------------
__global__ __launch_bounds__(256) void prep_w(
    const float* __restrict__ wg, const float* __restrict__ wn,
    unsigned char* __restrict__ wsb)
{
  const int t  = blockIdx.x * 256 + threadIdx.x;   // 0..32767
  const int l  = t & 63;
  const int nt = (t >> 6) & 3;
  const int g  = t >> 8;                           // 0..127 (16-k steps)
  const int colg = nt * 32 + (l & 31);             // 0..127
  const int kb   = g * 16 + 8 * (l >> 5);
  const float* wsrc = (colg < EE) ? (wg + colg) : (wn + (colg - EE));

  unsigned hv[8], lv[8];
#pragma unroll
  for (int i = 0; i < 8; ++i) {
    const float v = wsrc[(size_t)(kb + i) * EE];
    const unsigned h = f2bf_rne(v);
    hv[i] = h;
    lv[i] = f2bf_rne(v - bf2f(h));
  }
  uint4 hq, lq;
  hq.x = hv[0] | (hv[1] << 16); hq.y = hv[2] | (hv[3] << 16);
  hq.z = hv[4] | (hv[5] << 16); hq.w = hv[6] | (hv[7] << 16);
  lq.x = lv[0] | (lv[1] << 16); lq.y = lv[2] | (lv[3] << 16);
  lq.z = lv[4] | (lv[5] << 16); lq.w = lv[6] | (lv[7] << 16);

  const size_t base = ((size_t)(g * 4 + nt) * 2) * 1024 + (size_t)l * 16;
  *reinterpret_cast<uint4*>(wsb + base)        = hq;   // hi
  *reinterpret_cast<uint4*>(wsb + base + 1024) = lq;   // lo
}

union BF8 { bf16x8 v; ushort u[8]; };

__device__ __forceinline__ void cvt_hilo(const float4& a, const float4& b,
                                         bf16x8& hi, bf16x8& lo) {
  const float f[8] = {a.x, a.y, a.z, a.w, b.x, b.y, b.z, b.w};
  BF8 H, L;
#pragma unroll
  for (int i = 0; i < 8; ++i) {
    const unsigned u = __float_as_uint(f[i]);
    H.u[i] = (ushort)(u >> 16);                                 // exact prefix
    L.v[i] = (__bf16)(f[i] - __uint_as_float(u & 0xffff0000u)); // residual, RNE
  }
  hi = H.v; lo = L.v;
}

__device__ __forceinline__ bf16x8 bc(const uint4& q) {
  return __builtin_bit_cast(bf16x8, q);
}

// ---------------------------------------------------------------------------
// router_gemm v4: TLP over ILP. grid (256 m-tiles, 4 k-splits) = 1024 blocks
// = 4 blocks/CU; block = 256 thr = 4 waves (nt2 x kq2). Wave: 32 tok x
// 64 cols x 256 k = 16 ksteps of {2 x-loads + 4 B-loads (L2-hot ws) +
// in-reg fp32->bf16 hi/lo + 6 mfma_32x32x16 (3-term)}. ~96 total regs
// (32 acc AGPR + ~64 VGPR) under the 128 cap -> 16 waves/CU resident,
// double R3. Latency is hidden by waves, not by a register pipeline the
// allocator keeps collapsing (R2/R3 post-mortems). kq-reduce via 16 KB
// LDS, partials [tok][4][128] (R0-proven 16 MB ws + epilogue layout).
// ---------------------------------------------------------------------------
__global__ __launch_bounds__(256, 4) void router_gemm(
    const float* __restrict__ x,
    const unsigned char* __restrict__ wsb,
    float* __restrict__ part)          // [NTOK][KSPLIT][128]
{
  __shared__ float Lp[BM][128];        // 16 KB

  const int tid  = threadIdx.x;
  const int w    = tid >> 6;           // 0..3
  const int lane = tid & 63;
  const int nt2  = w & 1;              // 64-col half
  const int kq   = w >> 1;             // 256-k half of this block's k-range
  const int tok0 = blockIdx.x * BM;
  const int ks   = blockIdx.y;

  const int kbase = ks * 512 + kq * 256;
  // A: lane l -> x[tok0+(l&31)][kbase + 16 s + 8*(l>>5) + 0..7]
  const float* xp = x + (size_t)(tok0 + (lane & 31)) * DD
                      + kbase + 8 * (lane >> 5);
  // B: g16 = kbase/16 + s ; frags nt = 2*nt2, 2*nt2+1 (hi at +0, lo at +1024)
  const unsigned char* bp = wsb
      + ((size_t)((kbase >> 4) * 4 + 2 * nt2)) * 2048 + (size_t)lane * 16;

  f32x16 a0 = {0.f,0.f,0.f,0.f,0.f,0.f,0.f,0.f,0.f,0.f,0.f,0.f,0.f,0.f,0.f,0.f};
  f32x16 a1 = a0;

#pragma unroll
  for (int s = 0; s < NKS; ++s) {
    const float* p = xp + 16 * s;
    const float4 xa = *reinterpret_cast<const float4*>(p);
    const float4 xb = *reinterpret_cast<const float4*>(p + 4);
    const unsigned char* q = bp + (size_t)8192 * s;
    const uint4 bh0 = *reinterpret_cast<const uint4*>(q);
    const uint4 bl0 = *reinterpret_cast<const uint4*>(q + 1024);
    const uint4 bh1 = *reinterpret_cast<const uint4*>(q + 2048);
    const uint4 bl1 = *reinterpret_cast<const uint4*>(q + 3072);

    bf16x8 ahi, alo;
    cvt_hilo(xa, xb, ahi, alo);
    a0 = __builtin_amdgcn_mfma_f32_32x32x16_bf16(ahi, bc(bh0), a0, 0, 0, 0);
    a0 = __builtin_amdgcn_mfma_f32_32x32x16_bf16(ahi, bc(bl0), a0, 0, 0, 0);
    a0 = __builtin_amdgcn_mfma_f32_32x32x16_bf16(alo, bc(bh0), a0, 0, 0, 0);
    a1 = __builtin_amdgcn_mfma_f32_32x32x16_bf16(ahi, bc(bh1), a1, 0, 0, 0);
    a1 = __builtin_amdgcn_mfma_f32_32x32x16_bf16(ahi, bc(bl1), a1, 0, 0, 0);
    a1 = __builtin_amdgcn_mfma_f32_32x32x16_bf16(alo, bc(bh1), a1, 0, 0, 0);
  }

  // ---- kq-reduce (2 phases). C/D map (validated R1-R3): col = lane&31,
  // row = (q&3) + 8*(q>>2) + 4*(lane>>5) ----
  const int ccol  = 64 * nt2 + (lane & 31);
  const int crow0 = 4 * (lane >> 5);
  if (kq == 0) {
#pragma unroll
    for (int q = 0; q < 16; ++q) {
      const int row = (q & 3) + 8 * (q >> 2) + crow0;
      Lp[row][ccol]      = a0[q];
      Lp[row][ccol + 32] = a1[q];
    }
  }
  __syncthreads();
  if (kq == 1) {
#pragma unroll
    for (int q = 0; q < 16; ++q) {
      const int row = (q & 3) + 8 * (q >> 2) + crow0;
      Lp[row][ccol]      += a0[q];
      Lp[row][ccol + 32] += a1[q];
    }
  }
  __syncthreads();

  // ---- store: wave w writes rows [8w, 8w+8), float2 per lane ----
#pragma unroll
  for (int rr = 0; rr < 8; ++rr) {
    const int r = 8 * w + rr;
    const float2 v = *reinterpret_cast<const float2*>(&Lp[r][2 * lane]);
    *reinterpret_cast<float2*>(
        part + ((size_t)(tok0 + r) * KSPLIT + ks) * 128 + 2 * lane) = v;
  }
}

// ---------------------------------------------------------------------------
// Epilogue (R0-proven, verbatim semantics): one wave per token. Sum KSPLIT
// partials, softplus-noise, top-2 (desc value, asc index), softmax over 2,
// scatter probs + indices + one-hot masks.
// ---------------------------------------------------------------------------
__global__ __launch_bounds__(256) void router_epilogue(
    const float* __restrict__ part,      // [NTOK][KSPLIT][128]
    const float* __restrict__ noise_eps, // [NTOK][EE]
    float* __restrict__ out)
{
  const int t    = blockIdx.x * 4 + (threadIdx.x >> 6);
  const int lane = threadIdx.x & 63;

  const float* p = part + (size_t)t * KSPLIT * 128;
  float g = 0.0f, nraw = 0.0f;
#pragma unroll
  for (int s = 0; s < KSPLIT; ++s) {
    g    += p[s * 128 + lane];
    nraw += p[s * 128 + EE + lane];
  }
  const float ep = noise_eps[(size_t)t * EE + lane];

  const float sp = fmaxf(nraw, 0.0f) + log1pf(expf(-fabsf(nraw)));
  const float z  = fmaf(sp, ep, g);

  float v1 = z; int i1 = lane;
#pragma unroll
  for (int off = 32; off >= 1; off >>= 1) {
    const float ov = __shfl_xor(v1, off, 64);
    const int   oi = __shfl_xor(i1, off, 64);
    if (ov > v1 || (ov == v1 && oi < i1)) { v1 = ov; i1 = oi; }
  }
  float v2 = (lane == i1) ? -INFINITY : z; int i2 = lane;
#pragma unroll
  for (int off = 32; off >= 1; off >>= 1) {
    const float ov = __shfl_xor(v2, off, 64);
    const int   oi = __shfl_xor(i2, off, 64);
    if (ov > v2 || (ov == v2 && oi < i2)) { v2 = ov; i2 = oi; }
  }

  const float e2 = expf(v2 - v1);
  const float denom = 1.0f + e2;
  const float p1 = 1.0f / denom;
  const float p2 = e2 / denom;

  out[PROB_OFF + (size_t)t * EE + lane] =
      (lane == i1) ? p1 : ((lane == i2) ? p2 : 0.0f);

  if (lane == 0) {
    out[IDX_OFF + t * 2 + 0] = (float)i1;
    out[IDX_OFF + t * 2 + 1] = (float)i2;
  }

  out[MASK_OFF + 0 * MASK_K_STRIDE + (size_t)t * EE + lane] = (lane == i1) ? 1.0f : 0.0f;
  out[MASK_OFF + 1 * MASK_K_STRIDE + (size_t)t * EE + lane] = (lane == i2) ? 1.0f : 0.0f;
}

// ---------------------------------------------------------------------------
extern "C" void kernel_launch(void* const* d_in, const int* in_sizes, int n_in,
                              void* d_out, int out_size, void* d_ws, size_t ws_size,
                              hipStream_t stream) {
  const float* x   = (const float*)d_in[0];
  const float* eps = (const float*)d_in[1];
  const float* wg  = (const float*)d_in[2];
  const float* wn  = (const float*)d_in[3];

  unsigned char* wsb = (unsigned char*)d_ws;            // 1 MB weight frags
  float* part = (float*)(wsb + (1 << 20));              // 16 MB partials

  prep_w<<<dim3(128), dim3(256), 0, stream>>>(wg, wn, wsb);
  router_gemm<<<dim3(NTOK / BM, KSPLIT), dim3(256), 0, stream>>>(x, wsb, part);
  router_epilogue<<<dim3(NTOK / 4), dim3(256), 0, stream>>>(part, eps,
                                                            (float*)d_out);
}

// Round 5
// 126.483 us; speedup vs baseline: 1.0836x; 1.0836x over previous
//
#include <hip/hip_runtime.h>
#include <math.h>

// Problem constants
#define DD    2048
#define EE    64
#define NTOK  8192
#define BM    32                // tokens per block
#define NKH   16                // 16 kh-waves, 128 k each
#define NKS   8                 // ksteps (16 k) per wave

// Output layout (all read back as float32 by harness)
#define PROB_OFF 0
#define IDX_OFF  524288
#define MASK_OFF 540672
#define MASK_K_STRIDE (NTOK * EE)

typedef __bf16 bf16x8 __attribute__((ext_vector_type(8)));
typedef float  f32x16 __attribute__((ext_vector_type(16)));

__device__ __forceinline__ unsigned f2bf_rne(float f) {
  unsigned u = __float_as_uint(f);
  return (u + 0x7fffu + ((u >> 16) & 1u)) >> 16;   // low 16 bits = bf16
}
__device__ __forceinline__ float bf2f(unsigned h) {
  return __uint_as_float(h << 16);
}

// ---------------------------------------------------------------------------
// prep_w: weights -> MFMA-fragment-ready bf16 hi/lo in workspace (1 MB).
// Fragment bijection (validated end-to-end by R1-R4 passes):
//   slot (g, nt, mat, lane, i)  <->  B[k][c],  k = 16*g + 8*(lane>>5) + i,
//   c = 32*nt + (lane&31),  (c<64 -> gate, else noise).
// Byte addr = ((g*4 + nt)*2 + mat)*1024 + lane*16 + 2*i.
// ---------------------------------------------------------------------------
__global__ __launch_bounds__(256) void prep_w(
    const float* __restrict__ wg, const float* __restrict__ wn,
    unsigned char* __restrict__ wsb)
{
  const int t  = blockIdx.x * 256 + threadIdx.x;   // 0..32767
  const int l  = t & 63;
  const int nt = (t >> 6) & 3;
  const int g  = t >> 8;                           // 0..127 (16-k steps)
  const int colg = nt * 32 + (l & 31);             // 0..127
  const int kb   = g * 16 + 8 * (l >> 5);
  const float* wsrc = (colg < EE) ? (wg + colg) : (wn + (colg - EE));

  unsigned hv[8], lv[8];
#pragma unroll
  for (int i = 0; i < 8; ++i) {
    const float v = wsrc[(size_t)(kb + i) * EE];
    const unsigned h = f2bf_rne(v);
    hv[i] = h;
    lv[i] = f2bf_rne(v - bf2f(h));
  }
  uint4 hq, lq;
  hq.x = hv[0] | (hv[1] << 16); hq.y = hv[2] | (hv[3] << 16);
  hq.z = hv[4] | (hv[5] << 16); hq.w = hv[6] | (hv[7] << 16);
  lq.x = lv[0] | (lv[1] << 16); lq.y = lv[2] | (lv[3] << 16);
  lq.z = lv[4] | (lv[5] << 16); lq.w = lv[6] | (lv[7] << 16);

  const size_t base = ((size_t)(g * 4 + nt) * 2) * 1024 + (size_t)l * 16;
  *reinterpret_cast<uint4*>(wsb + base)        = hq;   // hi
  *reinterpret_cast<uint4*>(wsb + base + 1024) = lq;   // lo
}

union BF8 { bf16x8 v; ushort u[8]; };

__device__ __forceinline__ void cvt_hilo(const float4& a, const float4& b,
                                         bf16x8& hi, bf16x8& lo) {
  const float f[8] = {a.x, a.y, a.z, a.w, b.x, b.y, b.z, b.w};
  BF8 H, L;
#pragma unroll
  for (int i = 0; i < 8; ++i) {
    const unsigned u = __float_as_uint(f[i]);
    H.u[i] = (ushort)(u >> 16);                                 // exact prefix
    L.v[i] = (__bf16)(f[i] - __uint_as_float(u & 0xffff0000u)); // residual, RNE
  }
  hi = H.v; lo = L.v;
}

__device__ __forceinline__ bf16x8 bc(const uint4& q) {
  return __builtin_bit_cast(bf16x8, q);
}

// ---------------------------------------------------------------------------
// router_fused v5: occupancy A/B vs R3. 256 blocks x 1024 thr = 16 kh-waves
// per block; a 16-wave block forces 4 waves/SIMD co-resident (16 waves/CU,
// 2x R3) with the SAME per-CU VMEM instruction count as R3 (~1280): if the
// 46-50 us plateau is exposed latency, this halves it; if it is VMEM issue
// rate, it won't (and that becomes the next target). Wave kh: full 32tok x
// 128col tile over 128 k (8 ksteps of {2 x-loads + 8 B-loads (L2-hot ws) +
// in-reg fp32->bf16 hi/lo + 12 mfma}). Kstep computed in two nt-halves so
// live regs fit the 128-reg budget 1024thr implies (acc=64 AGPR). No
// barriers in the k-loop; 4-phase slab reduce in 64 KB LDS; in-block
// epilogue (R2-verbatim). 2 launches total.
// ---------------------------------------------------------------------------
__global__ __launch_bounds__(1024) void router_fused(
    const float* __restrict__ x,
    const float* __restrict__ noise_eps,
    const unsigned char* __restrict__ wsb,
    float* __restrict__ out)
{
  __shared__ float Lp[4][BM][128];    // 64 KB kh-slabs; used post-loop only

  const int tid  = threadIdx.x;
  const int wid  = tid >> 6;          // 0..15 = kh
  const int lane = tid & 63;
  const int kh   = wid;
  const int tok0 = blockIdx.x * BM;

  // A: lane l -> x[tok0+(l&31)][kh*128 + 16 s + 8*(l>>5) + 0..7]
  const float* xp = x + (size_t)(tok0 + (lane & 31)) * DD
                      + kh * 128 + 8 * (lane >> 5);
  // B: g = kh*8 + s; bytes g*8192 + nt*2048 + mat*1024 + lane*16
  const unsigned char* bp = wsb + (size_t)kh * 65536 + (size_t)lane * 16;

  f32x16 a0 = {0.f,0.f,0.f,0.f,0.f,0.f,0.f,0.f,0.f,0.f,0.f,0.f,0.f,0.f,0.f,0.f};
  f32x16 a1 = a0, a2 = a0, a3 = a0;

#pragma unroll
  for (int s = 0; s < NKS; ++s) {
    const float* p = xp + 16 * s;
    const float4 xa = *reinterpret_cast<const float4*>(p);
    const float4 xb = *reinterpret_cast<const float4*>(p + 4);
    const unsigned char* q = bp + (size_t)8192 * s;

    bf16x8 ahi, alo;
    cvt_hilo(xa, xb, ahi, alo);

    // half 1: nt0, nt1
    {
      const uint4 bh0 = *reinterpret_cast<const uint4*>(q);
      const uint4 bl0 = *reinterpret_cast<const uint4*>(q + 1024);
      const uint4 bh1 = *reinterpret_cast<const uint4*>(q + 2048);
      const uint4 bl1 = *reinterpret_cast<const uint4*>(q + 3072);
      a0 = __builtin_amdgcn_mfma_f32_32x32x16_bf16(ahi, bc(bh0), a0, 0, 0, 0);
      a0 = __builtin_amdgcn_mfma_f32_32x32x16_bf16(ahi, bc(bl0), a0, 0, 0, 0);
      a0 = __builtin_amdgcn_mfma_f32_32x32x16_bf16(alo, bc(bh0), a0, 0, 0, 0);
      a1 = __builtin_amdgcn_mfma_f32_32x32x16_bf16(ahi, bc(bh1), a1, 0, 0, 0);
      a1 = __builtin_amdgcn_mfma_f32_32x32x16_bf16(ahi, bc(bl1), a1, 0, 0, 0);
      a1 = __builtin_amdgcn_mfma_f32_32x32x16_bf16(alo, bc(bh1), a1, 0, 0, 0);
    }
    // half 2: nt2, nt3
    {
      const uint4 bh2 = *reinterpret_cast<const uint4*>(q + 4096);
      const uint4 bl2 = *reinterpret_cast<const uint4*>(q + 5120);
      const uint4 bh3 = *reinterpret_cast<const uint4*>(q + 6144);
      const uint4 bl3 = *reinterpret_cast<const uint4*>(q + 7168);
      a2 = __builtin_amdgcn_mfma_f32_32x32x16_bf16(ahi, bc(bh2), a2, 0, 0, 0);
      a2 = __builtin_amdgcn_mfma_f32_32x32x16_bf16(ahi, bc(bl2), a2, 0, 0, 0);
      a2 = __builtin_amdgcn_mfma_f32_32x32x16_bf16(alo, bc(bh2), a2, 0, 0, 0);
      a3 = __builtin_amdgcn_mfma_f32_32x32x16_bf16(ahi, bc(bh3), a3, 0, 0, 0);
      a3 = __builtin_amdgcn_mfma_f32_32x32x16_bf16(ahi, bc(bl3), a3, 0, 0, 0);
      a3 = __builtin_amdgcn_mfma_f32_32x32x16_bf16(alo, bc(bh3), a3, 0, 0, 0);
    }
  }

  // ---- kh-reduce: 4 slabs x 4 phases. C/D map (validated R1-R4):
  // col = lane&31, row = (q&3) + 8*(q>>2) + 4*(lane>>5) ----
  const int slab  = kh & 3;
  const int phase = kh >> 2;
  const int ccol  = lane & 31;
  const int crow0 = 4 * (lane >> 5);
#pragma unroll
  for (int ph = 0; ph < 4; ++ph) {
    if (phase == ph) {
      if (ph == 0) {
#pragma unroll
        for (int q = 0; q < 16; ++q) {
          const int row = (q & 3) + 8 * (q >> 2) + crow0;
          Lp[slab][row][ccol]      = a0[q];
          Lp[slab][row][ccol + 32] = a1[q];
          Lp[slab][row][ccol + 64] = a2[q];
          Lp[slab][row][ccol + 96] = a3[q];
        }
      } else {
#pragma unroll
        for (int q = 0; q < 16; ++q) {
          const int row = (q & 3) + 8 * (q >> 2) + crow0;
          Lp[slab][row][ccol]      += a0[q];
          Lp[slab][row][ccol + 32] += a1[q];
          Lp[slab][row][ccol + 64] += a2[q];
          Lp[slab][row][ccol + 96] += a3[q];
        }
      }
    }
    __syncthreads();
  }

  // ---- epilogue: 16 waves x 2 tokens; lane = expert (R2-verbatim) ----
#pragma unroll
  for (int it = 0; it < 2; ++it) {
    const int tl  = wid * 2 + it;
    const int tok = tok0 + tl;

    const float g    = Lp[0][tl][lane] + Lp[1][tl][lane]
                     + Lp[2][tl][lane] + Lp[3][tl][lane];
    const float nraw = Lp[0][tl][64 + lane] + Lp[1][tl][64 + lane]
                     + Lp[2][tl][64 + lane] + Lp[3][tl][64 + lane];
    const float ep   = noise_eps[(size_t)tok * EE + lane];

    const float sp = fmaxf(nraw, 0.0f) + log1pf(expf(-fabsf(nraw)));
    const float z  = fmaf(sp, ep, g);

    float v1 = z; int i1 = lane;
#pragma unroll
    for (int off = 32; off >= 1; off >>= 1) {
      const float ov = __shfl_xor(v1, off, 64);
      const int   oi = __shfl_xor(i1, off, 64);
      if (ov > v1 || (ov == v1 && oi < i1)) { v1 = ov; i1 = oi; }
    }
    float v2 = (lane == i1) ? -INFINITY : z; int i2 = lane;
#pragma unroll
    for (int off = 32; off >= 1; off >>= 1) {
      const float ov = __shfl_xor(v2, off, 64);
      const int   oi = __shfl_xor(i2, off, 64);
      if (ov > v2 || (ov == v2 && oi < i2)) { v2 = ov; i2 = oi; }
    }

    const float e2 = expf(v2 - v1);
    const float denom = 1.0f + e2;
    const float p1 = 1.0f / denom;
    const float p2 = e2 / denom;

    out[PROB_OFF + (size_t)tok * EE + lane] =
        (lane == i1) ? p1 : ((lane == i2) ? p2 : 0.0f);
    if (lane == 0) {
      out[IDX_OFF + tok * 2 + 0] = (float)i1;
      out[IDX_OFF + tok * 2 + 1] = (float)i2;
    }
    out[MASK_OFF + 0 * MASK_K_STRIDE + (size_t)tok * EE + lane] =
        (lane == i1) ? 1.0f : 0.0f;
    out[MASK_OFF + 1 * MASK_K_STRIDE + (size_t)tok * EE + lane] =
        (lane == i2) ? 1.0f : 0.0f;
  }
}

// ---------------------------------------------------------------------------
extern "C" void kernel_launch(void* const* d_in, const int* in_sizes, int n_in,
                              void* d_out, int out_size, void* d_ws, size_t ws_size,
                              hipStream_t stream) {
  const float* x   = (const float*)d_in[0];
  const float* eps = (const float*)d_in[1];
  const float* wg  = (const float*)d_in[2];
  const float* wn  = (const float*)d_in[3];
  unsigned char* wsb = (unsigned char*)d_ws;   // 1 MB bf16 hi/lo weight frags

  prep_w<<<dim3(128), dim3(256), 0, stream>>>(wg, wn, wsb);
  router_fused<<<dim3(NTOK / BM), dim3(1024), 0, stream>>>(x, eps, wsb,
                                                           (float*)d_out);
}

// Round 6
// 125.884 us; speedup vs baseline: 1.0887x; 1.0048x over previous
//
#include <hip/hip_runtime.h>
#include <math.h>

// Problem constants
#define DD     2048
#define EE     64
#define NTOK   8192
#define BM     32               // tokens per m-tile
#define KSPLIT 2                // K-split across blockIdx.y
#define KHALF  1024             // k per block
#define BK     64               // k per staged chunk
#define NCH    (KHALF / BK)     // 16 chunks

// Output layout (all read back as float32 by harness)
#define PROB_OFF 0
#define IDX_OFF  524288
#define MASK_OFF 540672
#define MASK_K_STRIDE (NTOK * EE)

// LDS byte layout: xbuf[2] @ 0/8192 (8 KB each), bbuf[2] @ 16384/49152 (32 KB)
#define XBUF_OFF(b) ((b) * 8192)
#define BBUF_OFF(b) (16384 + (b) * 32768)
#define LDS_BYTES   81920

typedef __bf16 bf16x8 __attribute__((ext_vector_type(8)));
typedef float  f32x16 __attribute__((ext_vector_type(16)));

__device__ __forceinline__ unsigned f2bf_rne(float f) {
  unsigned u = __float_as_uint(f);
  return (u + 0x7fffu + ((u >> 16) & 1u)) >> 16;   // low 16 bits = bf16
}
__device__ __forceinline__ float bf2f(unsigned h) {
  return __uint_as_float(h << 16);
}

// async 16B global->LDS DMA (no VGPR round-trip; tracked by vmcnt)
__device__ __forceinline__ void gl_lds16(const void* g, void* l) {
  __builtin_amdgcn_global_load_lds(
      (const __attribute__((address_space(1))) unsigned int*)g,
      (__attribute__((address_space(3))) unsigned int*)l,
      16, 0, 0);
}

// ---------------------------------------------------------------------------
// prep_w: weights -> MFMA-fragment-ready bf16 hi/lo in workspace (1 MB).
// Fragment bijection (validated end-to-end by R1-R5 passes):
//   slot (g, nt, mat, lane, i)  <->  B[k][c],  k = 16*g + 8*(lane>>5) + i,
//   c = 32*nt + (lane&31),  (c<64 -> gate, else noise).
// Byte addr = ((g*4 + nt)*2 + mat)*1024 + lane*16 + 2*i.
// ---------------------------------------------------------------------------
__global__ __launch_bounds__(256) void prep_w(
    const float* __restrict__ wg, const float* __restrict__ wn,
    unsigned char* __restrict__ wsb)
{
  const int t  = blockIdx.x * 256 + threadIdx.x;   // 0..32767
  const int l  = t & 63;
  const int nt = (t >> 6) & 3;
  const int g  = t >> 8;                           // 0..127 (16-k steps)
  const int colg = nt * 32 + (l & 31);             // 0..127
  const int kb   = g * 16 + 8 * (l >> 5);
  const float* wsrc = (colg < EE) ? (wg + colg) : (wn + (colg - EE));

  unsigned hv[8], lv[8];
#pragma unroll
  for (int i = 0; i < 8; ++i) {
    const float v = wsrc[(size_t)(kb + i) * EE];
    const unsigned h = f2bf_rne(v);
    hv[i] = h;
    lv[i] = f2bf_rne(v - bf2f(h));
  }
  uint4 hq, lq;
  hq.x = hv[0] | (hv[1] << 16); hq.y = hv[2] | (hv[3] << 16);
  hq.z = hv[4] | (hv[5] << 16); hq.w = hv[6] | (hv[7] << 16);
  lq.x = lv[0] | (lv[1] << 16); lq.y = lv[2] | (lv[3] << 16);
  lq.z = lv[4] | (lv[5] << 16); lq.w = lv[6] | (lv[7] << 16);

  const size_t base = ((size_t)(g * 4 + nt) * 2) * 1024 + (size_t)l * 16;
  *reinterpret_cast<uint4*>(wsb + base)        = hq;   // hi
  *reinterpret_cast<uint4*>(wsb + base + 1024) = lq;   // lo
}

union BF8 { bf16x8 v; ushort u[8]; };

__device__ __forceinline__ void cvt_hilo(const float4& a, const float4& b,
                                         bf16x8& hi, bf16x8& lo) {
  const float f[8] = {a.x, a.y, a.z, a.w, b.x, b.y, b.z, b.w};
  BF8 H, L;
#pragma unroll
  for (int i = 0; i < 8; ++i) {
    const unsigned u = __float_as_uint(f[i]);
    H.u[i] = (ushort)(u >> 16);                                 // exact prefix
    L.v[i] = (__bf16)(f[i] - __uint_as_float(u & 0xffff0000u)); // residual, RNE
  }
  hi = H.v; lo = L.v;
}

__device__ __forceinline__ bf16x8 bc(const uint4& q) {
  return __builtin_bit_cast(bf16x8, q);
}

// ---------------------------------------------------------------------------
// router_gemm v6 (m97 structure): loads decoupled from VGPRs via
// global_load_lds (the R2-R5 plateau was allocator-serialized loads, proven
// by the R5 occupancy A/B: 2x waves, 0% faster). Grid (256 m, 2 ksplit) =
// 512 blocks = 2 blocks/CU (drain overlap); block = 256 thr = 4 nt-waves.
// Per BK=64 chunk: stage x 8 KB (global-source XOR-preswizzled by
// ((row&15)<<4) so strided A-frag ds_reads are conflict-free, rule #21) +
// B 32 KB (linear; contiguous-1KB ds_reads are the conflict-free pattern)
// into an 80 KB double buffer; each wave: 4 ksteps x {2 A ds_read_b128 +
// 2 B ds_read_b128 + cvt + 3 mfma_32x32x16}. One barrier/chunk. Tail:
// acc -> LDS [32][128] -> coalesced partials [tok][2][128].
// ---------------------------------------------------------------------------
__global__ __launch_bounds__(256, 2) void router_gemm(
    const float* __restrict__ x,
    const unsigned char* __restrict__ wsb,
    float* __restrict__ part)          // [NTOK][KSPLIT][128]
{
  __shared__ unsigned char lds[LDS_BYTES];

  const int tid  = threadIdx.x;
  const int wid  = tid >> 6;           // 0..3 = nt
  const int lane = tid & 63;
  const int nt   = wid;
  const int tok0 = blockIdx.x * BM;
  const int ks   = blockIdx.y;

  // ---- staging roles (x pre-swizzled at the GLOBAL source) ----
  // slot u (0..511) <-> LDS byte u*16; row = u>>4, 16B-slot = u&15;
  // content = x[row][chunk k-base + ((u&15) ^ (row&15)) * 4 floats]
  const int row0 = tid >> 4;           // u = tid      -> rows 0..15
  const int sl0  = tid & 15;
  const float* xsrc0 = x + (size_t)(tok0 + row0) * DD + ks * KHALF
                         + ((sl0 ^ (row0 & 15)) << 2);
  const float* xsrc1 = x + (size_t)(tok0 + row0 + 16) * DD + ks * KHALF
                         + ((sl0 ^ ((row0 + 16) & 15)) << 2);
  const unsigned char* bsrc = wsb + (size_t)ks * (KHALF / 16) * 8192
                                  + (size_t)tid * 16;

  // ---- compute-role constants ----
  const int arow = lane & 31;          // token within tile
  const int atl  = lane >> 5;
  const int aswz = (arow & 15) << 4;   // read-side swizzle (matches source)

  f32x16 acc = {0.f,0.f,0.f,0.f,0.f,0.f,0.f,0.f,
                0.f,0.f,0.f,0.f,0.f,0.f,0.f,0.f};

  // ---- stage chunk 0, then one-chunk-lookahead pipeline ----
  {
    gl_lds16(xsrc0, &lds[XBUF_OFF(0) + tid * 16]);
    gl_lds16(xsrc1, &lds[XBUF_OFF(0) + 4096 + tid * 16]);
#pragma unroll
    for (int j = 0; j < 8; ++j)
      gl_lds16(bsrc + j * 4096, &lds[BBUF_OFF(0) + j * 4096 + tid * 16]);
  }
  __syncthreads();   // compiler drains vmcnt(0) here (m97 semantics)

  for (int c = 0; c < NCH; ++c) {
    const int cb = c & 1;

    if (c + 1 < NCH) {   // stage chunk c+1 into the other buffer (async DMA)
      const int nb = cb ^ 1;
      gl_lds16(xsrc0 + (c + 1) * BK, &lds[XBUF_OFF(nb) + tid * 16]);
      gl_lds16(xsrc1 + (c + 1) * BK, &lds[XBUF_OFF(nb) + 4096 + tid * 16]);
      const unsigned char* bs = bsrc + (size_t)(c + 1) * 32768;
#pragma unroll
      for (int j = 0; j < 8; ++j)
        gl_lds16(bs + j * 4096, &lds[BBUF_OFF(nb) + j * 4096 + tid * 16]);
    }

    // ---- compute chunk c from buffer cb (LDS only) ----
    const unsigned char* xb = &lds[XBUF_OFF(cb)];
    const unsigned char* bb = &lds[BBUF_OFF(cb)];
#pragma unroll
    for (int s = 0; s < 4; ++s) {
      const int koff = s * 64 + atl * 32;
      const float4 xa = *reinterpret_cast<const float4*>(
          xb + arow * 256 + (koff ^ aswz));
      const float4 xv = *reinterpret_cast<const float4*>(
          xb + arow * 256 + ((koff + 16) ^ aswz));
      const unsigned char* q = bb + (s * 4 + nt) * 2048 + lane * 16;
      const uint4 bh = *reinterpret_cast<const uint4*>(q);
      const uint4 bl = *reinterpret_cast<const uint4*>(q + 1024);

      bf16x8 ahi, alo;
      cvt_hilo(xa, xv, ahi, alo);
      acc = __builtin_amdgcn_mfma_f32_32x32x16_bf16(ahi, bc(bh), acc, 0, 0, 0);
      acc = __builtin_amdgcn_mfma_f32_32x32x16_bf16(ahi, bc(bl), acc, 0, 0, 0);
      acc = __builtin_amdgcn_mfma_f32_32x32x16_bf16(alo, bc(bh), acc, 0, 0, 0);
    }
    __syncthreads();   // readers of cb done; staged c+1 drained (vmcnt 0)
  }

  // ---- tail: acc -> LDS [32][128] (overlays x buffers), coalesced store ----
  // C/D map (validated R1-R5): col = lane&31, row = (q&3)+8*(q>>2)+4*(lane>>5)
  float* Lp = reinterpret_cast<float*>(lds);
  const int ccol = nt * 32 + (lane & 31);
#pragma unroll
  for (int q = 0; q < 16; ++q) {
    const int r = (q & 3) + 8 * (q >> 2) + 4 * atl;
    Lp[r * 128 + ccol] = acc[q];
  }
  __syncthreads();
#pragma unroll
  for (int rr = 0; rr < 8; ++rr) {
    const int r = 8 * wid + rr;
    const float2 v = *reinterpret_cast<const float2*>(&Lp[r * 128 + 2 * lane]);
    *reinterpret_cast<float2*>(
        part + ((size_t)(tok0 + r) * KSPLIT + ks) * 128 + 2 * lane) = v;
  }
}

// ---------------------------------------------------------------------------
// Epilogue (R0/R4-proven): one wave per token. Sum KSPLIT partials,
// softplus-noise, top-2 (desc value, asc index), softmax over 2, scatter.
// ---------------------------------------------------------------------------
__global__ __launch_bounds__(256) void router_epilogue(
    const float* __restrict__ part,      // [NTOK][KSPLIT][128]
    const float* __restrict__ noise_eps, // [NTOK][EE]
    float* __restrict__ out)
{
  const int t    = blockIdx.x * 4 + (threadIdx.x >> 6);
  const int lane = threadIdx.x & 63;

  const float* p = part + (size_t)t * KSPLIT * 128;
  float g = 0.0f, nraw = 0.0f;
#pragma unroll
  for (int s = 0; s < KSPLIT; ++s) {
    g    += p[s * 128 + lane];
    nraw += p[s * 128 + EE + lane];
  }
  const float ep = noise_eps[(size_t)t * EE + lane];

  const float sp = fmaxf(nraw, 0.0f) + log1pf(expf(-fabsf(nraw)));
  const float z  = fmaf(sp, ep, g);

  float v1 = z; int i1 = lane;
#pragma unroll
  for (int off = 32; off >= 1; off >>= 1) {
    const float ov = __shfl_xor(v1, off, 64);
    const int   oi = __shfl_xor(i1, off, 64);
    if (ov > v1 || (ov == v1 && oi < i1)) { v1 = ov; i1 = oi; }
  }
  float v2 = (lane == i1) ? -INFINITY : z; int i2 = lane;
#pragma unroll
  for (int off = 32; off >= 1; off >>= 1) {
    const float ov = __shfl_xor(v2, off, 64);
    const int   oi = __shfl_xor(i2, off, 64);
    if (ov > v2 || (ov == v2 && oi < i2)) { v2 = ov; i2 = oi; }
  }

  const float e2 = expf(v2 - v1);
  const float denom = 1.0f + e2;
  const float p1 = 1.0f / denom;
  const float p2 = e2 / denom;

  out[PROB_OFF + (size_t)t * EE + lane] =
      (lane == i1) ? p1 : ((lane == i2) ? p2 : 0.0f);

  if (lane == 0) {
    out[IDX_OFF + t * 2 + 0] = (float)i1;
    out[IDX_OFF + t * 2 + 1] = (float)i2;
  }

  out[MASK_OFF + 0 * MASK_K_STRIDE + (size_t)t * EE + lane] = (lane == i1) ? 1.0f : 0.0f;
  out[MASK_OFF + 1 * MASK_K_STRIDE + (size_t)t * EE + lane] = (lane == i2) ? 1.0f : 0.0f;
}

// ---------------------------------------------------------------------------
extern "C" void kernel_launch(void* const* d_in, const int* in_sizes, int n_in,
                              void* d_out, int out_size, void* d_ws, size_t ws_size,
                              hipStream_t stream) {
  const float* x   = (const float*)d_in[0];
  const float* eps = (const float*)d_in[1];
  const float* wg  = (const float*)d_in[2];
  const float* wn  = (const float*)d_in[3];

  unsigned char* wsb = (unsigned char*)d_ws;            // 1 MB weight frags
  float* part = (float*)(wsb + (1 << 20));              // 8 MB partials

  prep_w<<<dim3(128), dim3(256), 0, stream>>>(wg, wn, wsb);
  router_gemm<<<dim3(NTOK / BM, KSPLIT), dim3(256), 0, stream>>>(x, wsb, part);
  router_epilogue<<<dim3(NTOK / 4), dim3(256), 0, stream>>>(part, eps,
                                                            (float*)d_out);
}